// Round 13
// baseline (180.858 us; speedup 1.0000x reference)
//
#include <hip/hip_runtime.h>
#include <hip/hip_bf16.h>
#include <cstdint>

using u16 = unsigned short;
typedef __attribute__((ext_vector_type(8))) short short8;
typedef __attribute__((ext_vector_type(8))) _Float16 f16x8;
typedef __attribute__((ext_vector_type(4))) float floatx4;

#define MFMA16(a, b, c) __builtin_amdgcn_mfma_f32_16x16x32_bf16((a), (b), (c), 0, 0, 0)
#define MFMAH(a, b, c)  __builtin_amdgcn_mfma_f32_16x16x32_f16((a), (b), (c), 0, 0, 0)

#define GLL(gp, lp) __builtin_amdgcn_global_load_lds( \
    (const __attribute__((address_space(1))) unsigned int*)(gp), \
    (__attribute__((address_space(3))) unsigned int*)(lp), 16, 0, 0)

// counted-vmcnt barrier (T4): wait for all but the newest N VMEM ops, then
// raw barrier; sched_barrier stops the scheduler from hoisting LDS reads or
// the next STAGE above the barrier (GLL->LDS aliasing is compiler-invisible).
#define WAITBAR(N) do { \
    asm volatile("s_waitcnt vmcnt(" #N ")" ::: "memory"); \
    __builtin_amdgcn_s_barrier(); \
    __builtin_amdgcn_sched_barrier(0); } while (0)

// ---------- scalar conversion helpers ----------
__device__ __forceinline__ u16 f2bf(float f) {
    union { float f; unsigned u; } v; v.f = f;
    return (u16)((v.u + 0x7FFFu + ((v.u >> 16) & 1u)) >> 16);
}
__device__ __forceinline__ u16 f2h(float f) {
    _Float16 h = (_Float16)f;
    return __builtin_bit_cast(u16, h);
}
__device__ __forceinline__ unsigned cvt_pk_bf16(float lo, float hi) {
    unsigned r;
    asm("v_cvt_pk_bf16_f32 %0, %1, %2" : "=v"(r) : "v"(lo), "v"(hi));
    return r;
}
__device__ __forceinline__ float fast_exp2(float x) {
#if __has_builtin(__builtin_amdgcn_exp2f)
    return __builtin_amdgcn_exp2f(x);
#else
    float r; asm("v_exp_f32 %0, %1" : "=v"(r) : "v"(x)); return r;
#endif
}
__device__ __forceinline__ float fast_rcp(float x) {
#if __has_builtin(__builtin_amdgcn_rcpf)
    return __builtin_amdgcn_rcpf(x);
#else
    float r; asm("v_rcp_f32 %0, %1" : "=v"(r) : "v"(x)); return r;
#endif
}

// ---------- fp32 -> fp16 cast (x) ----------
__global__ void cast_x_f16(const float* __restrict__ src, u16* __restrict__ dst, int n4) {
    int idx = blockIdx.x * blockDim.x + threadIdx.x;
    int stride = gridDim.x * blockDim.x;
    for (int i = idx; i < n4; i += stride) {
        float4 v = reinterpret_cast<const float4*>(src)[i];
        reinterpret_cast<ushort4*>(dst)[i] =
            make_ushort4(f2h(v.x), f2h(v.y), f2h(v.z), f2h(v.w));
    }
}

// ---------- all 4 weights -> fp16 ----------
__global__ void cast_w_f16(const float* q, const float* k, const float* v, const float* o,
                           u16* q16, u16* k16, u16* v16, u16* o16, int n4) {
    const float* src; u16* dst;
    switch (blockIdx.y) {
        case 0:  src = q; dst = q16; break;
        case 1:  src = k; dst = k16; break;
        case 2:  src = v; dst = v16; break;
        default: src = o; dst = o16; break;
    }
    int idx = blockIdx.x * blockDim.x + threadIdx.x;
    int stride = gridDim.x * blockDim.x;
    for (int i = idx; i < n4; i += stride) {
        float4 w = reinterpret_cast<const float4*>(src)[i];
        reinterpret_cast<ushort4*>(dst)[i] =
            make_ushort4(f2h(w.x), f2h(w.y), f2h(w.z), f2h(w.w));
    }
}

// ---------- fp16 NT GEMM core, 128x128 tile, depth-2 counted-vmcnt pipeline ----------
// 4 LDS buffers; phase k: WAITBAR(4) [tile k staged] -> STAGE(k+2) -> compute(k&3).
// mode 0: bf16 [bh][t][dk] (Q,K)
// mode 1: bf16 [bh][dk][t] with per-64-key slot permutation (V transposed)
// mode 2: fp32 [t][d] (final output)
__device__ __forceinline__ void gemm_core(
    const u16* __restrict__ A16, const u16* __restrict__ B16,
    const float* __restrict__ bias, u16* __restrict__ out16,
    float* __restrict__ outf, int mode, float scale, char* ldsb) {
    int flat = blockIdx.x + (blockIdx.y << 6);
    int swz = (flat & 7) * 64 + (flat >> 3);
    const int m0 = ((swz >> 6) * 8 + ((swz >> 3) & 7)) << 7;
    const int n0 = (swz & 7) << 7;

    const int t = threadIdx.x, lane = t & 63, w = t >> 6;
    const int c = lane & 15, g = lane >> 4;
    const int wm = w & 1, wn = w >> 1;

    floatx4 zero = {0.f, 0.f, 0.f, 0.f};
    floatx4 acc[4][4];
#pragma unroll
    for (int mf = 0; mf < 4; ++mf)
#pragma unroll
        for (int nf = 0; nf < 4; ++nf) acc[mf][nf] = zero;

    const u16* gsrc[2] = {A16 + (size_t)m0 * 1024, B16 + (size_t)n0 * 1024};

    int dst_db[4];
    size_t src_el[4];
#pragma unroll
    for (int j = 0; j < 4; ++j) {
        int db = t * 16 + j * 4096;
        int local = db & 8191;
        int row = local >> 6;
        int colsw = (local & 63) ^ (((local >> 7) & 3) << 4);
        dst_db[j] = db;
        src_el[j] = (size_t)row * 1024 + (colsw >> 1);
    }

    int offA[4], offB[4];
#pragma unroll
    for (int f = 0; f < 4; ++f) {
        int rA = wm * 64 + f * 16 + c;
        offA[f] = rA * 64 + ((g * 16) ^ (((rA >> 1) & 3) << 4));
        int rB = wn * 64 + f * 16 + c;
        offB[f] = 8192 + rB * 64 + ((g * 16) ^ (((rB >> 1) & 3) << 4));
    }

#define GSTAGE(BUF, K0) do { \
    _Pragma("unroll") \
    for (int j = 0; j < 4; ++j) \
        GLL(gsrc[j >> 1] + src_el[j] + (K0), ldsb + (BUF) * 16384 + dst_db[j]); \
    } while (0)

    GSTAGE(0, 0);
    GSTAGE(1, 32);
    for (int k = 0; k < 32; ++k) {
        if (k == 31) {
            asm volatile("s_waitcnt vmcnt(0)" ::: "memory");
        } else {
            asm volatile("s_waitcnt vmcnt(4)" ::: "memory");
        }
        __builtin_amdgcn_s_barrier();
        __builtin_amdgcn_sched_barrier(0);
        if (k + 2 < 32) GSTAGE((k + 2) & 3, (k + 2) * 32);
        const char* lb = ldsb + (k & 3) * 16384;

        f16x8 a[4], b[4];
#pragma unroll
        for (int f = 0; f < 4; ++f) {
            a[f] = *reinterpret_cast<const f16x8*>(lb + offA[f]);
            b[f] = *reinterpret_cast<const f16x8*>(lb + offB[f]);
        }
#pragma unroll
        for (int mf = 0; mf < 4; ++mf)
#pragma unroll
            for (int nf = 0; nf < 4; ++nf)
                acc[mf][nf] = MFMAH(a[mf], b[nf], acc[mf][nf]);
    }
#undef GSTAGE

#pragma unroll
    for (int nf = 0; nf < 4; ++nf) {
        int col = n0 + wn * 64 + nf * 16 + c;
        float bv = bias[col];
#pragma unroll
        for (int mf = 0; mf < 4; ++mf) {
            int rb = m0 + wm * 64 + mf * 16 + 4 * g;
            if (mode == 2) {
#pragma unroll
                for (int i = 0; i < 4; ++i)
                    outf[(size_t)(rb + i) * 1024 + col] = (acc[mf][nf][i] + bv) * scale;
            } else {
                int b = rb >> 11, tt = rb & 2047, h = col >> 6, dk = col & 63;
                if (mode == 0) {
#pragma unroll
                    for (int i = 0; i < 4; ++i)
                        out16[((size_t)(b * 16 + h) * 2048 + tt + i) * 64 + dk] =
                            f2bf((acc[mf][nf][i] + bv) * scale);
                } else {
                    // key k=16q+4s+i -> pos (q>>1)*32 + s*8 + (q&1)*4 + i
                    ushort4 pk;
                    pk.x = f2bf((acc[mf][nf][0] + bv) * scale);
                    pk.y = f2bf((acc[mf][nf][1] + bv) * scale);
                    pk.z = f2bf((acc[mf][nf][2] + bv) * scale);
                    pk.w = f2bf((acc[mf][nf][3] + bv) * scale);
                    int k64 = tt & 63, q = k64 >> 4, sub = (k64 >> 2) & 3;
                    int pos = ((q >> 1) << 5) + (sub << 3) + ((q & 1) << 2);
                    *reinterpret_cast<ushort4*>(
                        out16 + ((size_t)(b * 16 + h) * 64 + dk) * 2048 +
                        (tt & ~63) + pos) = pk;
                }
            }
        }
    }
}

// QKV fused: grid.z selects projection
__global__ __launch_bounds__(256) void gemm_qkv(
    const u16* __restrict__ x16,
    const u16* __restrict__ Wq, const u16* __restrict__ Wk, const u16* __restrict__ Wv,
    const float* __restrict__ bq, const float* __restrict__ bk, const float* __restrict__ bv,
    u16* __restrict__ Qb, u16* __restrict__ Kb, u16* __restrict__ Vtb, float qscale) {
    __shared__ __align__(16) char lds[4][16384];
    if (blockIdx.z == 0)      gemm_core(x16, Wq, bq, Qb,  nullptr, 0, qscale, (char*)lds);
    else if (blockIdx.z == 1) gemm_core(x16, Wk, bk, Kb,  nullptr, 0, 1.0f, (char*)lds);
    else                      gemm_core(x16, Wv, bv, Vtb, nullptr, 1, 1.0f, (char*)lds);
}

__global__ __launch_bounds__(256) void gemm_o(
    const u16* __restrict__ cx, const u16* __restrict__ Wo,
    const float* __restrict__ bo, float* __restrict__ out) {
    __shared__ __align__(16) char lds[4][16384];
    gemm_core(cx, Wo, bo, nullptr, out, 2, 1.0f, (char*)lds);
}

// ---------- flash attention: QBLK=128, 8 waves, T15 + depth-2 counted-vmcnt ----------
// 4 LDS buffers (16KB each: K 8KB | V 8KB). Phase p: WAITBAR(2) [tile p staged,
// tile p+1 may be in flight] -> STAGE(p+2) -> QK(p) + PV(p-1) + exp/cvt(p).
__global__ __launch_bounds__(512) void attn_flash(
    const u16* __restrict__ Q, const u16* __restrict__ K, const u16* __restrict__ Vt,
    u16* __restrict__ ctx) {
    __shared__ __align__(16) char kv_lds[4][16384];

    int flat = blockIdx.x + (blockIdx.y << 4);        // 1024 wgs
    int swz = (flat & 7) * 128 + (flat >> 3);         // XCD-contiguous, bijective
    const int q0 = (swz & 15) << 7;
    const int bh = swz >> 4;

    const int lane = threadIdx.x & 63, w = threadIdx.x >> 6;   // w = 0..7
    const int c = lane & 15, g = lane >> 4;

    const u16* qrow = Q + ((size_t)bh * 2048 + q0 + w * 16 + c) * 64;
    short8 qf0 = *reinterpret_cast<const short8*>(qrow + g * 8);
    short8 qf1 = *reinterpret_cast<const short8*>(qrow + 32 + g * 8);

    const bool isK = (w < 4);
    const char* sptr = isK ? (const char*)(K + (size_t)bh * 2048 * 64)
                           : (const char*)(Vt + (size_t)bh * 64 * 2048);
    const int sadv = isK ? 8192 : 128;                // bytes per 64-key tile
    size_t src_off[2];
    int dst_off[2];
#pragma unroll
    for (int j = 0; j < 2; ++j) {
        int base = (w & 3) * 2048 + j * 1024 + lane * 16;
        int row = base >> 7, col = (base & 127) ^ ((row & 7) << 4);
        if (isK) { dst_off[j] = base;        src_off[j] = (size_t)row * 128  + col; }
        else     { dst_off[j] = 8192 + base; src_off[j] = (size_t)row * 4096 + col; }
    }

    const int sw = (c & 7) << 4;
    const int abase0 = c * 128 + ((g * 16) ^ sw);
    const int abase1 = c * 128 + ((64 + g * 16) ^ sw);

    short8 ones;
#pragma unroll
    for (int e = 0; e < 8; ++e) ones[e] = (short)0x3F80;   // bf16 1.0

    floatx4 zero = {0.f, 0.f, 0.f, 0.f};
    floatx4 acc[4] = {zero, zero, zero, zero};            // ctx[q=4g+i][d=nt*16+c]
    floatx4 acc5 = zero;                                  // rowsum[q=4g+i]

    union pa_t { unsigned u[4]; short8 s; };
    pa_t paA0, paA1, paB0, paB1;
    short8 vrA[8], vrB[8];

#define STAGE_TO(BUF) do { \
    GLL(sptr + src_off[0], (char*)kv_lds + (BUF) * 16384 + dst_off[0]); \
    GLL(sptr + src_off[1], (char*)kv_lds + (BUF) * 16384 + dst_off[1]); \
    sptr += sadv; } while (0)

#define PHASE(N, BUF, SBUF, DO_STAGE, PAc0, PAc1, VRc, PAp0, PAp1, VRp, DO_PV) do { \
    WAITBAR(N); \
    if (DO_STAGE) STAGE_TO(SBUF); \
    const char* kbL = (const char*)kv_lds + (BUF) * 16384; \
    floatx4 st[4]; \
    __builtin_amdgcn_s_setprio(1); \
    _Pragma("unroll") \
    for (int kf = 0; kf < 4; ++kf) { \
        short8 k0 = *reinterpret_cast<const short8*>(kbL + kf * 2048 + abase0); \
        short8 k1 = *reinterpret_cast<const short8*>(kbL + kf * 2048 + abase1); \
        st[kf] = MFMA16(k1, qf1, MFMA16(k0, qf0, zero)); \
    } \
    if (DO_PV) { \
        acc5 = MFMA16(PAp0.s, ones, acc5); \
        acc5 = MFMA16(PAp1.s, ones, acc5); \
        _Pragma("unroll") \
        for (int nt = 0; nt < 4; ++nt) \
            acc[nt] = MFMA16(PAp1.s, VRp[nt + 4], MFMA16(PAp0.s, VRp[nt], acc[nt])); \
    } \
    __builtin_amdgcn_s_setprio(0); \
    _Pragma("unroll") \
    for (int nt = 0; nt < 4; ++nt) { \
        VRc[nt]     = *reinterpret_cast<const short8*>(kbL + 8192 + nt * 2048 + abase0); \
        VRc[nt + 4] = *reinterpret_cast<const short8*>(kbL + 8192 + nt * 2048 + abase1); \
    } \
    float p[4][4]; \
    _Pragma("unroll") \
    for (int kf = 0; kf < 4; ++kf) \
        _Pragma("unroll") \
        for (int i = 0; i < 4; ++i) p[kf][i] = fast_exp2(st[kf][i]); \
    PAc0.u[0] = cvt_pk_bf16(p[0][0], p[0][1]); \
    PAc0.u[1] = cvt_pk_bf16(p[0][2], p[0][3]); \
    PAc0.u[2] = cvt_pk_bf16(p[1][0], p[1][1]); \
    PAc0.u[3] = cvt_pk_bf16(p[1][2], p[1][3]); \
    PAc1.u[0] = cvt_pk_bf16(p[2][0], p[2][1]); \
    PAc1.u[1] = cvt_pk_bf16(p[2][2], p[2][3]); \
    PAc1.u[2] = cvt_pk_bf16(p[3][0], p[3][1]); \
    PAc1.u[3] = cvt_pk_bf16(p[3][2], p[3][3]); \
    } while (0)

    STAGE_TO(0);                                      // tile 0
    STAGE_TO(1);                                      // tile 1
    // phases 0..3 (tile == phase; buf = phase&3; stage tile p+2 -> buf (p+2)&3)
    PHASE(2, 0, 2, 1, paA0, paA1, vrA, paB0, paB1, vrB, 0);
    PHASE(2, 1, 3, 1, paB0, paB1, vrB, paA0, paA1, vrA, 1);
    PHASE(2, 2, 0, 1, paA0, paA1, vrA, paB0, paB1, vrB, 1);
    PHASE(2, 3, 1, 1, paB0, paB1, vrB, paA0, paA1, vrA, 1);
    // phases 4..27
    for (int it = 0; it < 6; ++it) {
        PHASE(2, 0, 2, 1, paA0, paA1, vrA, paB0, paB1, vrB, 1);
        PHASE(2, 1, 3, 1, paB0, paB1, vrB, paA0, paA1, vrA, 1);
        PHASE(2, 2, 0, 1, paA0, paA1, vrA, paB0, paB1, vrB, 1);
        PHASE(2, 3, 1, 1, paB0, paB1, vrB, paA0, paA1, vrA, 1);
    }
    // phases 28..31 (28 stages tile 30, 29 stages tile 31, 30/31 no stage)
    PHASE(2, 0, 2, 1, paA0, paA1, vrA, paB0, paB1, vrB, 1);
    PHASE(2, 1, 3, 1, paB0, paB1, vrB, paA0, paA1, vrA, 1);
    PHASE(2, 2, 0, 0, paA0, paA1, vrA, paB0, paB1, vrB, 1);
    PHASE(0, 3, 1, 0, paB0, paB1, vrB, paA0, paA1, vrA, 1);
    // final PV (tile 31, regs B)
    acc5 = MFMA16(paB0.s, ones, acc5);
    acc5 = MFMA16(paB1.s, ones, acc5);
#pragma unroll
    for (int nt = 0; nt < 4; ++nt)
        acc[nt] = MFMA16(paB1.s, vrB[nt + 4], MFMA16(paB0.s, vrB[nt], acc[nt]));
#undef STAGE_TO
#undef PHASE

    const int b = bh >> 4, h = bh & 15;
    float rl[4];
#pragma unroll
    for (int i = 0; i < 4; ++i) rl[i] = fast_rcp(acc5[i]);
#pragma unroll
    for (int nt = 0; nt < 4; ++nt) {
#pragma unroll
        for (int i = 0; i < 4; ++i) {
            int tt = q0 + w * 16 + 4 * g + i;
            size_t idx = ((size_t)b * 2048 + tt) * 1024 + h * 64 + nt * 16 + c;
            ctx[idx] = f2h(acc[nt][i] * rl[i]);
        }
    }
}

extern "C" void kernel_launch(void* const* d_in, const int* in_sizes, int n_in,
                              void* d_out, int out_size, void* d_ws, size_t ws_size,
                              hipStream_t stream) {
    if (n_in < 9) return;
    const float* x  = (const float*)d_in[0];
    const float* Wq = (const float*)d_in[1];
    const float* bq = (const float*)d_in[2];
    const float* Wk = (const float*)d_in[3];
    const float* bk = (const float*)d_in[4];
    const float* Wv = (const float*)d_in[5];
    const float* bv = (const float*)d_in[6];
    const float* Wo = (const float*)d_in[7];
    const float* bo = (const float*)d_in[8];
    float* out = (float*)d_out;

    const size_t NX = 8192ull * 1024ull;
    const size_t NW = 1024ull * 1024ull;
    u16* p = (u16*)d_ws;
    u16* x16  = p; p += NX;
    u16* Wq16 = p; p += NW;
    u16* Wk16 = p; p += NW;
    u16* Wv16 = p; p += NW;
    u16* Wo16 = p; p += NW;
    u16* Qb   = p; p += NX;
    u16* Kb   = p; p += NX;
    u16* Vtb  = p; p += NX;
    u16* cx   = p; p += NX;
    if ((size_t)((char*)p - (char*)d_ws) > ws_size) return;

    dim3 blk(256);
    cast_x_f16<<<dim3(2048), blk, 0, stream>>>(x, x16, (int)(NX / 4));
    cast_w_f16<<<dim3(256, 4), blk, 0, stream>>>(
        Wq, Wk, Wv, Wo, Wq16, Wk16, Wv16, Wo16, (int)(NW / 4));

    const float qscale = 0.125f * 1.44269504088896f;   // fold 1/sqrt(dk) * log2(e)
    gemm_qkv<<<dim3(64, 8, 3), blk, 0, stream>>>(
        x16, Wq16, Wk16, Wv16, bq, bk, bv, Qb, Kb, Vtb, qscale);

    attn_flash<<<dim3(16, 64), dim3(512), 0, stream>>>(Qb, Kb, Vtb, cx);

    gemm_o<<<dim3(64, 8), blk, 0, stream>>>(cx, Wo16, bo, out);
}

// Round 14
// 174.325 us; speedup vs baseline: 1.0375x; 1.0375x over previous
//
#include <hip/hip_runtime.h>
#include <hip/hip_bf16.h>
#include <cstdint>

using u16 = unsigned short;
typedef __attribute__((ext_vector_type(8))) short short8;
typedef __attribute__((ext_vector_type(8))) _Float16 f16x8;
typedef __attribute__((ext_vector_type(4))) float floatx4;

#define MFMA16(a, b, c) __builtin_amdgcn_mfma_f32_16x16x32_bf16((a), (b), (c), 0, 0, 0)
#define MFMAH(a, b, c)  __builtin_amdgcn_mfma_f32_16x16x32_f16((a), (b), (c), 0, 0, 0)

#define GLL(gp, lp) __builtin_amdgcn_global_load_lds( \
    (const __attribute__((address_space(1))) unsigned int*)(gp), \
    (__attribute__((address_space(3))) unsigned int*)(lp), 16, 0, 0)

// ---------- scalar conversion helpers ----------
__device__ __forceinline__ u16 f2bf(float f) {
    union { float f; unsigned u; } v; v.f = f;
    return (u16)((v.u + 0x7FFFu + ((v.u >> 16) & 1u)) >> 16);
}
__device__ __forceinline__ u16 f2h(float f) {
    _Float16 h = (_Float16)f;
    return __builtin_bit_cast(u16, h);
}
__device__ __forceinline__ unsigned cvt_pk_bf16(float lo, float hi) {
    unsigned r;
    asm("v_cvt_pk_bf16_f32 %0, %1, %2" : "=v"(r) : "v"(lo), "v"(hi));
    return r;
}
__device__ __forceinline__ float fast_exp2(float x) {
#if __has_builtin(__builtin_amdgcn_exp2f)
    return __builtin_amdgcn_exp2f(x);
#else
    float r; asm("v_exp_f32 %0, %1" : "=v"(r) : "v"(x)); return r;
#endif
}
__device__ __forceinline__ float fast_rcp(float x) {
#if __has_builtin(__builtin_amdgcn_rcpf)
    return __builtin_amdgcn_rcpf(x);
#else
    float r; asm("v_rcp_f32 %0, %1" : "=v"(r) : "v"(x)); return r;
#endif
}

// ---------- fp32 -> fp16 cast (x) ----------
__global__ void cast_x_f16(const float* __restrict__ src, u16* __restrict__ dst, int n4) {
    int idx = blockIdx.x * blockDim.x + threadIdx.x;
    int stride = gridDim.x * blockDim.x;
    for (int i = idx; i < n4; i += stride) {
        float4 v = reinterpret_cast<const float4*>(src)[i];
        reinterpret_cast<ushort4*>(dst)[i] =
            make_ushort4(f2h(v.x), f2h(v.y), f2h(v.z), f2h(v.w));
    }
}

// ---------- all 4 weights -> fp16 ----------
__global__ void cast_w_f16(const float* q, const float* k, const float* v, const float* o,
                           u16* q16, u16* k16, u16* v16, u16* o16, int n4) {
    const float* src; u16* dst;
    switch (blockIdx.y) {
        case 0:  src = q; dst = q16; break;
        case 1:  src = k; dst = k16; break;
        case 2:  src = v; dst = v16; break;
        default: src = o; dst = o16; break;
    }
    int idx = blockIdx.x * blockDim.x + threadIdx.x;
    int stride = gridDim.x * blockDim.x;
    for (int i = idx; i < n4; i += stride) {
        float4 w = reinterpret_cast<const float4*>(src)[i];
        reinterpret_cast<ushort4*>(dst)[i] =
            make_ushort4(f2h(w.x), f2h(w.y), f2h(w.z), f2h(w.w));
    }
}

// ---------- fp16 NT GEMM core, 128x128 tile, double-buffered LDS (R10) ----------
// mode 0: bf16 [bh][t][dk] (Q,K)
// mode 1: bf16 [bh][dk][t] with per-64-key slot permutation (V transposed)
// mode 2: fp32 [t][d] (final output)
__device__ __forceinline__ void gemm_core(
    const u16* __restrict__ A16, const u16* __restrict__ B16,
    const float* __restrict__ bias, u16* __restrict__ out16,
    float* __restrict__ outf, int mode, float scale, char* ldsb) {
    int flat = blockIdx.x + (blockIdx.y << 6);
    int swz = (flat & 7) * 64 + (flat >> 3);
    const int m0 = ((swz >> 6) * 8 + ((swz >> 3) & 7)) << 7;
    const int n0 = (swz & 7) << 7;

    const int t = threadIdx.x, lane = t & 63, w = t >> 6;
    const int c = lane & 15, g = lane >> 4;
    const int wm = w & 1, wn = w >> 1;

    floatx4 zero = {0.f, 0.f, 0.f, 0.f};
    floatx4 acc[4][4];
#pragma unroll
    for (int mf = 0; mf < 4; ++mf)
#pragma unroll
        for (int nf = 0; nf < 4; ++nf) acc[mf][nf] = zero;

    const u16* gsrc[2] = {A16 + (size_t)m0 * 1024, B16 + (size_t)n0 * 1024};

    int dst_db[4];
    size_t src_el[4];
#pragma unroll
    for (int j = 0; j < 4; ++j) {
        int db = t * 16 + j * 4096;
        int local = db & 8191;
        int row = local >> 6;
        int colsw = (local & 63) ^ (((local >> 7) & 3) << 4);
        dst_db[j] = db;
        src_el[j] = (size_t)row * 1024 + (colsw >> 1);
    }

    int offA[4], offB[4];
#pragma unroll
    for (int f = 0; f < 4; ++f) {
        int rA = wm * 64 + f * 16 + c;
        offA[f] = rA * 64 + ((g * 16) ^ (((rA >> 1) & 3) << 4));
        int rB = wn * 64 + f * 16 + c;
        offB[f] = 8192 + rB * 64 + ((g * 16) ^ (((rB >> 1) & 3) << 4));
    }

#define GSTAGE(BUF, K0) do { \
    _Pragma("unroll") \
    for (int j = 0; j < 4; ++j) \
        GLL(gsrc[j >> 1] + src_el[j] + (K0), ldsb + (BUF) * 16384 + dst_db[j]); \
    } while (0)

    GSTAGE(0, 0);
    for (int k0 = 0; k0 < 1024; k0 += 32) {
        const int cur = (k0 >> 5) & 1;
        __syncthreads();
        if (k0 + 32 < 1024) GSTAGE(cur ^ 1, k0 + 32);
        const char* lb = ldsb + cur * 16384;

        f16x8 a[4], b[4];
#pragma unroll
        for (int f = 0; f < 4; ++f) {
            a[f] = *reinterpret_cast<const f16x8*>(lb + offA[f]);
            b[f] = *reinterpret_cast<const f16x8*>(lb + offB[f]);
        }
#pragma unroll
        for (int mf = 0; mf < 4; ++mf)
#pragma unroll
            for (int nf = 0; nf < 4; ++nf)
                acc[mf][nf] = MFMAH(a[mf], b[nf], acc[mf][nf]);
    }
#undef GSTAGE

#pragma unroll
    for (int nf = 0; nf < 4; ++nf) {
        int col = n0 + wn * 64 + nf * 16 + c;
        float bv = bias[col];
#pragma unroll
        for (int mf = 0; mf < 4; ++mf) {
            int rb = m0 + wm * 64 + mf * 16 + 4 * g;
            if (mode == 2) {
#pragma unroll
                for (int i = 0; i < 4; ++i)
                    outf[(size_t)(rb + i) * 1024 + col] = (acc[mf][nf][i] + bv) * scale;
            } else {
                int b = rb >> 11, tt = rb & 2047, h = col >> 6, dk = col & 63;
                if (mode == 0) {
#pragma unroll
                    for (int i = 0; i < 4; ++i)
                        out16[((size_t)(b * 16 + h) * 2048 + tt + i) * 64 + dk] =
                            f2bf((acc[mf][nf][i] + bv) * scale);
                } else {
                    // key k=16q+4s+i -> pos (q>>1)*32 + s*8 + (q&1)*4 + i
                    ushort4 pk;
                    pk.x = f2bf((acc[mf][nf][0] + bv) * scale);
                    pk.y = f2bf((acc[mf][nf][1] + bv) * scale);
                    pk.z = f2bf((acc[mf][nf][2] + bv) * scale);
                    pk.w = f2bf((acc[mf][nf][3] + bv) * scale);
                    int k64 = tt & 63, q = k64 >> 4, sub = (k64 >> 2) & 3;
                    int pos = ((q >> 1) << 5) + (sub << 3) + ((q & 1) << 2);
                    *reinterpret_cast<ushort4*>(
                        out16 + ((size_t)(b * 16 + h) * 64 + dk) * 2048 +
                        (tt & ~63) + pos) = pk;
                }
            }
        }
    }
}

// QKV fused: grid.z selects projection
__global__ __launch_bounds__(256) void gemm_qkv(
    const u16* __restrict__ x16,
    const u16* __restrict__ Wq, const u16* __restrict__ Wk, const u16* __restrict__ Wv,
    const float* __restrict__ bq, const float* __restrict__ bk, const float* __restrict__ bv,
    u16* __restrict__ Qb, u16* __restrict__ Kb, u16* __restrict__ Vtb, float qscale) {
    __shared__ __align__(16) char lds[2][16384];
    if (blockIdx.z == 0)      gemm_core(x16, Wq, bq, Qb,  nullptr, 0, qscale, (char*)lds);
    else if (blockIdx.z == 1) gemm_core(x16, Wk, bk, Kb,  nullptr, 0, 1.0f, (char*)lds);
    else                      gemm_core(x16, Wv, bv, Vtb, nullptr, 1, 1.0f, (char*)lds);
}

__global__ __launch_bounds__(256) void gemm_o(
    const u16* __restrict__ cx, const u16* __restrict__ Wo,
    const float* __restrict__ bo, float* __restrict__ out) {
    __shared__ __align__(16) char lds[2][16384];
    gemm_core(cx, Wo, bo, nullptr, out, 2, 1.0f, (char*)lds);
}

// ---------- flash attention: QBLK=128, 8 waves, T15 pipeline (R10 base) ----------
// Change vs R10: no scheduling fence between PV MFMAs and exp/cvt — setprio
// spans the whole phase body, so the compiler may interleave the independent
// exp/cvt VALU ops into the PV accumulate-chain stall windows.
__global__ __launch_bounds__(512) void attn_flash(
    const u16* __restrict__ Q, const u16* __restrict__ K, const u16* __restrict__ Vt,
    u16* __restrict__ ctx) {
    __shared__ __align__(16) char kv_lds[2][16384];   // [buf][K 8KB | V 8KB]

    int flat = blockIdx.x + (blockIdx.y << 4);        // 1024 wgs
    int swz = (flat & 7) * 128 + (flat >> 3);         // XCD-contiguous, bijective
    const int q0 = (swz & 15) << 7;
    const int bh = swz >> 4;

    const int lane = threadIdx.x & 63, w = threadIdx.x >> 6;   // w = 0..7
    const int c = lane & 15, g = lane >> 4;

    const u16* qrow = Q + ((size_t)bh * 2048 + q0 + w * 16 + c) * 64;
    short8 qf0 = *reinterpret_cast<const short8*>(qrow + g * 8);
    short8 qf1 = *reinterpret_cast<const short8*>(qrow + 32 + g * 8);

    const bool isK = (w < 4);
    const char* sptr = isK ? (const char*)(K + (size_t)bh * 2048 * 64)
                           : (const char*)(Vt + (size_t)bh * 64 * 2048);
    const int sadv = isK ? 8192 : 128;
    size_t src_off[2];
    int dst_off[2];
#pragma unroll
    for (int j = 0; j < 2; ++j) {
        int base = (w & 3) * 2048 + j * 1024 + lane * 16;
        int row = base >> 7, col = (base & 127) ^ ((row & 7) << 4);
        if (isK) { dst_off[j] = base;        src_off[j] = (size_t)row * 128  + col; }
        else     { dst_off[j] = 8192 + base; src_off[j] = (size_t)row * 4096 + col; }
    }

    const int sw = (c & 7) << 4;
    const int abase0 = c * 128 + ((g * 16) ^ sw);
    const int abase1 = c * 128 + ((64 + g * 16) ^ sw);

    short8 ones;
#pragma unroll
    for (int e = 0; e < 8; ++e) ones[e] = (short)0x3F80;   // bf16 1.0

    floatx4 zero = {0.f, 0.f, 0.f, 0.f};
    floatx4 acc[4] = {zero, zero, zero, zero};            // ctx[q=4g+i][d=nt*16+c]
    floatx4 acc5 = zero;                                  // rowsum[q=4g+i]

    union pa_t { unsigned u[4]; short8 s; };
    pa_t paA0, paA1, paB0, paB1;
    short8 vrA[8], vrB[8];

#define STAGE_TO(BUF) do { \
    GLL(sptr + src_off[0], (char*)kv_lds + (BUF) * 16384 + dst_off[0]); \
    GLL(sptr + src_off[1], (char*)kv_lds + (BUF) * 16384 + dst_off[1]); \
    sptr += sadv; } while (0)

#define PHASE(BUF, PAc0, PAc1, VRc, PAp0, PAp1, VRp, DO_PV, DO_STAGE) do { \
    __syncthreads(); \
    if (DO_STAGE) STAGE_TO((BUF) ^ 1); \
    const char* kbL = (const char*)kv_lds + (BUF) * 16384; \
    floatx4 st[4]; \
    __builtin_amdgcn_s_setprio(1); \
    _Pragma("unroll") \
    for (int kf = 0; kf < 4; ++kf) { \
        short8 k0 = *reinterpret_cast<const short8*>(kbL + kf * 2048 + abase0); \
        short8 k1 = *reinterpret_cast<const short8*>(kbL + kf * 2048 + abase1); \
        st[kf] = MFMA16(k1, qf1, MFMA16(k0, qf0, zero)); \
    } \
    _Pragma("unroll") \
    for (int nt = 0; nt < 4; ++nt) { \
        VRc[nt]     = *reinterpret_cast<const short8*>(kbL + 8192 + nt * 2048 + abase0); \
        VRc[nt + 4] = *reinterpret_cast<const short8*>(kbL + 8192 + nt * 2048 + abase1); \
    } \
    if (DO_PV) { \
        acc5 = MFMA16(PAp0.s, ones, acc5); \
        acc5 = MFMA16(PAp1.s, ones, acc5); \
        _Pragma("unroll") \
        for (int nt = 0; nt < 4; ++nt) \
            acc[nt] = MFMA16(PAp1.s, VRp[nt + 4], MFMA16(PAp0.s, VRp[nt], acc[nt])); \
    } \
    float p[4][4]; \
    _Pragma("unroll") \
    for (int kf = 0; kf < 4; ++kf) \
        _Pragma("unroll") \
        for (int i = 0; i < 4; ++i) p[kf][i] = fast_exp2(st[kf][i]); \
    PAc0.u[0] = cvt_pk_bf16(p[0][0], p[0][1]); \
    PAc0.u[1] = cvt_pk_bf16(p[0][2], p[0][3]); \
    PAc0.u[2] = cvt_pk_bf16(p[1][0], p[1][1]); \
    PAc0.u[3] = cvt_pk_bf16(p[1][2], p[1][3]); \
    PAc1.u[0] = cvt_pk_bf16(p[2][0], p[2][1]); \
    PAc1.u[1] = cvt_pk_bf16(p[2][2], p[2][3]); \
    PAc1.u[2] = cvt_pk_bf16(p[3][0], p[3][1]); \
    PAc1.u[3] = cvt_pk_bf16(p[3][2], p[3][3]); \
    __builtin_amdgcn_s_setprio(0); \
    } while (0)

    STAGE_TO(0);
    PHASE(0, paA0, paA1, vrA, paB0, paB1, vrB, 0, 1);
    for (int it = 0; it < 15; ++it) {
        PHASE(1, paB0, paB1, vrB, paA0, paA1, vrA, 1, 1);
        PHASE(0, paA0, paA1, vrA, paB0, paB1, vrB, 1, 1);
    }
    PHASE(1, paB0, paB1, vrB, paA0, paA1, vrA, 1, 0);
    acc5 = MFMA16(paB0.s, ones, acc5);
    acc5 = MFMA16(paB1.s, ones, acc5);
#pragma unroll
    for (int nt = 0; nt < 4; ++nt)
        acc[nt] = MFMA16(paB1.s, vrB[nt + 4], MFMA16(paB0.s, vrB[nt], acc[nt]));
#undef STAGE_TO
#undef PHASE

    const int b = bh >> 4, h = bh & 15;
    float rl[4];
#pragma unroll
    for (int i = 0; i < 4; ++i) rl[i] = fast_rcp(acc5[i]);
#pragma unroll
    for (int nt = 0; nt < 4; ++nt) {
#pragma unroll
        for (int i = 0; i < 4; ++i) {
            int tt = q0 + w * 16 + 4 * g + i;
            size_t idx = ((size_t)b * 2048 + tt) * 1024 + h * 64 + nt * 16 + c;
            ctx[idx] = f2h(acc[nt][i] * rl[i]);
        }
    }
}

extern "C" void kernel_launch(void* const* d_in, const int* in_sizes, int n_in,
                              void* d_out, int out_size, void* d_ws, size_t ws_size,
                              hipStream_t stream) {
    if (n_in < 9) return;
    const float* x  = (const float*)d_in[0];
    const float* Wq = (const float*)d_in[1];
    const float* bq = (const float*)d_in[2];
    const float* Wk = (const float*)d_in[3];
    const float* bk = (const float*)d_in[4];
    const float* Wv = (const float*)d_in[5];
    const float* bv = (const float*)d_in[6];
    const float* Wo = (const float*)d_in[7];
    const float* bo = (const float*)d_in[8];
    float* out = (float*)d_out;

    const size_t NX = 8192ull * 1024ull;
    const size_t NW = 1024ull * 1024ull;
    u16* p = (u16*)d_ws;
    u16* x16  = p; p += NX;
    u16* Wq16 = p; p += NW;
    u16* Wk16 = p; p += NW;
    u16* Wv16 = p; p += NW;
    u16* Wo16 = p; p += NW;
    u16* Qb   = p; p += NX;
    u16* Kb   = p; p += NX;
    u16* Vtb  = p; p += NX;
    u16* cx   = p; p += NX;
    if ((size_t)((char*)p - (char*)d_ws) > ws_size) return;

    dim3 blk(256);
    cast_x_f16<<<dim3(2048), blk, 0, stream>>>(x, x16, (int)(NX / 4));
    cast_w_f16<<<dim3(256, 4), blk, 0, stream>>>(
        Wq, Wk, Wv, Wo, Wq16, Wk16, Wv16, Wo16, (int)(NW / 4));

    const float qscale = 0.125f * 1.44269504088896f;   // fold 1/sqrt(dk) * log2(e)
    gemm_qkv<<<dim3(64, 8, 3), blk, 0, stream>>>(
        x16, Wq16, Wk16, Wv16, bq, bk, bv, Qb, Kb, Vtb, qscale);

    attn_flash<<<dim3(16, 64), dim3(512), 0, stream>>>(Qb, Kb, Vtb, cx);

    gemm_o<<<dim3(64, 8), blk, 0, stream>>>(cx, Wo16, bo, out);
}

// Round 17
// 169.038 us; speedup vs baseline: 1.0699x; 1.0313x over previous
//
#include <hip/hip_runtime.h>
#include <hip/hip_bf16.h>
#include <cstdint>

using u16 = unsigned short;
typedef __attribute__((ext_vector_type(8))) short short8;
typedef __attribute__((ext_vector_type(8))) _Float16 f16x8;
typedef __attribute__((ext_vector_type(4))) float floatx4;

#define MFMA16(a, b, c) __builtin_amdgcn_mfma_f32_16x16x32_bf16((a), (b), (c), 0, 0, 0)
#define MFMAH(a, b, c)  __builtin_amdgcn_mfma_f32_16x16x32_f16((a), (b), (c), 0, 0, 0)

#define GLL(gp, lp) __builtin_amdgcn_global_load_lds( \
    (const __attribute__((address_space(1))) unsigned int*)(gp), \
    (__attribute__((address_space(3))) unsigned int*)(lp), 16, 0, 0)

// ---------- scalar conversion helpers ----------
__device__ __forceinline__ u16 f2bf(float f) {
    union { float f; unsigned u; } v; v.f = f;
    return (u16)((v.u + 0x7FFFu + ((v.u >> 16) & 1u)) >> 16);
}
__device__ __forceinline__ u16 f2h(float f) {
    _Float16 h = (_Float16)f;
    return __builtin_bit_cast(u16, h);
}
__device__ __forceinline__ unsigned cvt_pk_bf16(float lo, float hi) {
    unsigned r;
    asm("v_cvt_pk_bf16_f32 %0, %1, %2" : "=v"(r) : "v"(lo), "v"(hi));
    return r;
}
__device__ __forceinline__ float fast_exp2(float x) {
#if __has_builtin(__builtin_amdgcn_exp2f)
    return __builtin_amdgcn_exp2f(x);
#else
    float r; asm("v_exp_f32 %0, %1" : "=v"(r) : "v"(x)); return r;
#endif
}
__device__ __forceinline__ float fast_rcp(float x) {
#if __has_builtin(__builtin_amdgcn_rcpf)
    return __builtin_amdgcn_rcpf(x);
#else
    float r; asm("v_rcp_f32 %0, %1" : "=v"(r) : "v"(x)); return r;
#endif
}

// ---------- all fp32 -> fp16 casts in ONE launch (grid.y selects tensor) ----------
__global__ void cast_all_f16(const float* x, const float* q, const float* k,
                             const float* v, const float* o,
                             u16* x16, u16* q16, u16* k16, u16* v16, u16* o16,
                             int nx4, int nw4) {
    const float* src; u16* dst; int n4;
    switch (blockIdx.y) {
        case 0:  src = x; dst = x16; n4 = nx4; break;
        case 1:  src = q; dst = q16; n4 = nw4; break;
        case 2:  src = k; dst = k16; n4 = nw4; break;
        case 3:  src = v; dst = v16; n4 = nw4; break;
        default: src = o; dst = o16; n4 = nw4; break;
    }
    int idx = blockIdx.x * blockDim.x + threadIdx.x;
    int stride = gridDim.x * blockDim.x;
    for (int i = idx; i < n4; i += stride) {
        float4 w = reinterpret_cast<const float4*>(src)[i];
        reinterpret_cast<ushort4*>(dst)[i] =
            make_ushort4(f2h(w.x), f2h(w.y), f2h(w.z), f2h(w.w));
    }
}

// ---------- fp16 NT GEMM core, 128x128 tile, double-buffered LDS (R10) ----------
// mode 0: bf16 [bh][t][dk] (Q,K)
// mode 1: bf16 [bh][dk][t] with per-64-key slot permutation (V transposed)
// mode 2: fp32 [t][d] (final output)
__device__ __forceinline__ void gemm_core(
    const u16* __restrict__ A16, const u16* __restrict__ B16,
    const float* __restrict__ bias, u16* __restrict__ out16,
    float* __restrict__ outf, int mode, float scale, char* ldsb) {
    int flat = blockIdx.x + (blockIdx.y << 6);
    int swz = (flat & 7) * 64 + (flat >> 3);
    const int m0 = ((swz >> 6) * 8 + ((swz >> 3) & 7)) << 7;
    const int n0 = (swz & 7) << 7;

    const int t = threadIdx.x, lane = t & 63, w = t >> 6;
    const int c = lane & 15, g = lane >> 4;
    const int wm = w & 1, wn = w >> 1;

    floatx4 zero = {0.f, 0.f, 0.f, 0.f};
    floatx4 acc[4][4];
#pragma unroll
    for (int mf = 0; mf < 4; ++mf)
#pragma unroll
        for (int nf = 0; nf < 4; ++nf) acc[mf][nf] = zero;

    const u16* gsrc[2] = {A16 + (size_t)m0 * 1024, B16 + (size_t)n0 * 1024};

    int dst_db[4];
    size_t src_el[4];
#pragma unroll
    for (int j = 0; j < 4; ++j) {
        int db = t * 16 + j * 4096;
        int local = db & 8191;
        int row = local >> 6;
        int colsw = (local & 63) ^ (((local >> 7) & 3) << 4);
        dst_db[j] = db;
        src_el[j] = (size_t)row * 1024 + (colsw >> 1);
    }

    int offA[4], offB[4];
#pragma unroll
    for (int f = 0; f < 4; ++f) {
        int rA = wm * 64 + f * 16 + c;
        offA[f] = rA * 64 + ((g * 16) ^ (((rA >> 1) & 3) << 4));
        int rB = wn * 64 + f * 16 + c;
        offB[f] = 8192 + rB * 64 + ((g * 16) ^ (((rB >> 1) & 3) << 4));
    }

#define GSTAGE(BUF, K0) do { \
    _Pragma("unroll") \
    for (int j = 0; j < 4; ++j) \
        GLL(gsrc[j >> 1] + src_el[j] + (K0), ldsb + (BUF) * 16384 + dst_db[j]); \
    } while (0)

    GSTAGE(0, 0);
    for (int k0 = 0; k0 < 1024; k0 += 32) {
        const int cur = (k0 >> 5) & 1;
        __syncthreads();
        if (k0 + 32 < 1024) GSTAGE(cur ^ 1, k0 + 32);
        const char* lb = ldsb + cur * 16384;

        f16x8 a[4], b[4];
#pragma unroll
        for (int f = 0; f < 4; ++f) {
            a[f] = *reinterpret_cast<const f16x8*>(lb + offA[f]);
            b[f] = *reinterpret_cast<const f16x8*>(lb + offB[f]);
        }
#pragma unroll
        for (int mf = 0; mf < 4; ++mf)
#pragma unroll
            for (int nf = 0; nf < 4; ++nf)
                acc[mf][nf] = MFMAH(a[mf], b[nf], acc[mf][nf]);
    }
#undef GSTAGE

#pragma unroll
    for (int nf = 0; nf < 4; ++nf) {
        int col = n0 + wn * 64 + nf * 16 + c;
        float bv = bias[col];
#pragma unroll
        for (int mf = 0; mf < 4; ++mf) {
            int rb = m0 + wm * 64 + mf * 16 + 4 * g;
            if (mode == 2) {
#pragma unroll
                for (int i = 0; i < 4; ++i)
                    outf[(size_t)(rb + i) * 1024 + col] = (acc[mf][nf][i] + bv) * scale;
            } else {
                int b = rb >> 11, tt = rb & 2047, h = col >> 6, dk = col & 63;
                if (mode == 0) {
#pragma unroll
                    for (int i = 0; i < 4; ++i)
                        out16[((size_t)(b * 16 + h) * 2048 + tt + i) * 64 + dk] =
                            f2bf((acc[mf][nf][i] + bv) * scale);
                } else {
                    // key k=16q+4s+i -> pos (q>>1)*32 + s*8 + (q&1)*4 + i
                    ushort4 pk;
                    pk.x = f2bf((acc[mf][nf][0] + bv) * scale);
                    pk.y = f2bf((acc[mf][nf][1] + bv) * scale);
                    pk.z = f2bf((acc[mf][nf][2] + bv) * scale);
                    pk.w = f2bf((acc[mf][nf][3] + bv) * scale);
                    int k64 = tt & 63, q = k64 >> 4, sub = (k64 >> 2) & 3;
                    int pos = ((q >> 1) << 5) + (sub << 3) + ((q & 1) << 2);
                    *reinterpret_cast<ushort4*>(
                        out16 + ((size_t)(b * 16 + h) * 64 + dk) * 2048 +
                        (tt & ~63) + pos) = pk;
                }
            }
        }
    }
}

// QKV fused: grid.z selects projection
__global__ __launch_bounds__(256) void gemm_qkv(
    const u16* __restrict__ x16,
    const u16* __restrict__ Wq, const u16* __restrict__ Wk, const u16* __restrict__ Wv,
    const float* __restrict__ bq, const float* __restrict__ bk, const float* __restrict__ bv,
    u16* __restrict__ Qb, u16* __restrict__ Kb, u16* __restrict__ Vtb, float qscale) {
    __shared__ __align__(16) char lds[2][16384];
    if (blockIdx.z == 0)      gemm_core(x16, Wq, bq, Qb,  nullptr, 0, qscale, (char*)lds);
    else if (blockIdx.z == 1) gemm_core(x16, Wk, bk, Kb,  nullptr, 0, 1.0f, (char*)lds);
    else                      gemm_core(x16, Wv, bv, Vtb, nullptr, 1, 1.0f, (char*)lds);
}

__global__ __launch_bounds__(256) void gemm_o(
    const u16* __restrict__ cx, const u16* __restrict__ Wo,
    const float* __restrict__ bo, float* __restrict__ out) {
    __shared__ __align__(16) char lds[2][16384];
    gemm_core(cx, Wo, bo, nullptr, out, 2, 1.0f, (char*)lds);
}

// ---------- flash attention: QBLK=128, 8 waves, T15 pipeline (R10 exact) ----------
__global__ __launch_bounds__(512) void attn_flash(
    const u16* __restrict__ Q, const u16* __restrict__ K, const u16* __restrict__ Vt,
    u16* __restrict__ ctx) {
    __shared__ __align__(16) char kv_lds[2][16384];   // [buf][K 8KB | V 8KB]

    int flat = blockIdx.x + (blockIdx.y << 4);        // 1024 wgs
    int swz = (flat & 7) * 128 + (flat >> 3);         // XCD-contiguous, bijective
    const int q0 = (swz & 15) << 7;
    const int bh = swz >> 4;

    const int lane = threadIdx.x & 63, w = threadIdx.x >> 6;   // w = 0..7
    const int c = lane & 15, g = lane >> 4;

    const u16* qrow = Q + ((size_t)bh * 2048 + q0 + w * 16 + c) * 64;
    short8 qf0 = *reinterpret_cast<const short8*>(qrow + g * 8);
    short8 qf1 = *reinterpret_cast<const short8*>(qrow + 32 + g * 8);

    const bool isK = (w < 4);
    const char* sptr = isK ? (const char*)(K + (size_t)bh * 2048 * 64)
                           : (const char*)(Vt + (size_t)bh * 64 * 2048);
    const int sadv = isK ? 8192 : 128;
    size_t src_off[2];
    int dst_off[2];
#pragma unroll
    for (int j = 0; j < 2; ++j) {
        int base = (w & 3) * 2048 + j * 1024 + lane * 16;
        int row = base >> 7, col = (base & 127) ^ ((row & 7) << 4);
        if (isK) { dst_off[j] = base;        src_off[j] = (size_t)row * 128  + col; }
        else     { dst_off[j] = 8192 + base; src_off[j] = (size_t)row * 4096 + col; }
    }

    const int sw = (c & 7) << 4;
    const int abase0 = c * 128 + ((g * 16) ^ sw);
    const int abase1 = c * 128 + ((64 + g * 16) ^ sw);

    short8 ones;
#pragma unroll
    for (int e = 0; e < 8; ++e) ones[e] = (short)0x3F80;   // bf16 1.0

    floatx4 zero = {0.f, 0.f, 0.f, 0.f};
    floatx4 acc[4] = {zero, zero, zero, zero};            // ctx[q=4g+i][d=nt*16+c]
    floatx4 acc5 = zero;                                  // rowsum[q=4g+i]

    union pa_t { unsigned u[4]; short8 s; };
    pa_t paA0, paA1, paB0, paB1;
    short8 vrA[8], vrB[8];

#define STAGE_TO(BUF) do { \
    GLL(sptr + src_off[0], (char*)kv_lds + (BUF) * 16384 + dst_off[0]); \
    GLL(sptr + src_off[1], (char*)kv_lds + (BUF) * 16384 + dst_off[1]); \
    sptr += sadv; } while (0)

#define PHASE(BUF, PAc0, PAc1, VRc, PAp0, PAp1, VRp, DO_PV, DO_STAGE) do { \
    __syncthreads(); \
    if (DO_STAGE) STAGE_TO((BUF) ^ 1); \
    const char* kbL = (const char*)kv_lds + (BUF) * 16384; \
    floatx4 st[4]; \
    __builtin_amdgcn_s_setprio(1); \
    _Pragma("unroll") \
    for (int kf = 0; kf < 4; ++kf) { \
        short8 k0 = *reinterpret_cast<const short8*>(kbL + kf * 2048 + abase0); \
        short8 k1 = *reinterpret_cast<const short8*>(kbL + kf * 2048 + abase1); \
        st[kf] = MFMA16(k1, qf1, MFMA16(k0, qf0, zero)); \
    } \
    if (DO_PV) { \
        acc5 = MFMA16(PAp0.s, ones, acc5); \
        acc5 = MFMA16(PAp1.s, ones, acc5); \
        _Pragma("unroll") \
        for (int nt = 0; nt < 4; ++nt) \
            acc[nt] = MFMA16(PAp1.s, VRp[nt + 4], MFMA16(PAp0.s, VRp[nt], acc[nt])); \
    } \
    __builtin_amdgcn_s_setprio(0); \
    _Pragma("unroll") \
    for (int nt = 0; nt < 4; ++nt) { \
        VRc[nt]     = *reinterpret_cast<const short8*>(kbL + 8192 + nt * 2048 + abase0); \
        VRc[nt + 4] = *reinterpret_cast<const short8*>(kbL + 8192 + nt * 2048 + abase1); \
    } \
    float p[4][4]; \
    _Pragma("unroll") \
    for (int kf = 0; kf < 4; ++kf) \
        _Pragma("unroll") \
        for (int i = 0; i < 4; ++i) p[kf][i] = fast_exp2(st[kf][i]); \
    PAc0.u[0] = cvt_pk_bf16(p[0][0], p[0][1]); \
    PAc0.u[1] = cvt_pk_bf16(p[0][2], p[0][3]); \
    PAc0.u[2] = cvt_pk_bf16(p[1][0], p[1][1]); \
    PAc0.u[3] = cvt_pk_bf16(p[1][2], p[1][3]); \
    PAc1.u[0] = cvt_pk_bf16(p[2][0], p[2][1]); \
    PAc1.u[1] = cvt_pk_bf16(p[2][2], p[2][3]); \
    PAc1.u[2] = cvt_pk_bf16(p[3][0], p[3][1]); \
    PAc1.u[3] = cvt_pk_bf16(p[3][2], p[3][3]); \
    } while (0)

    STAGE_TO(0);
    PHASE(0, paA0, paA1, vrA, paB0, paB1, vrB, 0, 1);
    for (int it = 0; it < 15; ++it) {
        PHASE(1, paB0, paB1, vrB, paA0, paA1, vrA, 1, 1);
        PHASE(0, paA0, paA1, vrA, paB0, paB1, vrB, 1, 1);
    }
    PHASE(1, paB0, paB1, vrB, paA0, paA1, vrA, 1, 0);
    acc5 = MFMA16(paB0.s, ones, acc5);
    acc5 = MFMA16(paB1.s, ones, acc5);
#pragma unroll
    for (int nt = 0; nt < 4; ++nt)
        acc[nt] = MFMA16(paB1.s, vrB[nt + 4], MFMA16(paB0.s, vrB[nt], acc[nt]));
#undef STAGE_TO
#undef PHASE

    const int b = bh >> 4, h = bh & 15;
    float rl[4];
#pragma unroll
    for (int i = 0; i < 4; ++i) rl[i] = fast_rcp(acc5[i]);
#pragma unroll
    for (int nt = 0; nt < 4; ++nt) {
#pragma unroll
        for (int i = 0; i < 4; ++i) {
            int tt = q0 + w * 16 + 4 * g + i;
            size_t idx = ((size_t)b * 2048 + tt) * 1024 + h * 64 + nt * 16 + c;
            ctx[idx] = f2h(acc[nt][i] * rl[i]);
        }
    }
}

extern "C" void kernel_launch(void* const* d_in, const int* in_sizes, int n_in,
                              void* d_out, int out_size, void* d_ws, size_t ws_size,
                              hipStream_t stream) {
    if (n_in < 9) return;
    const float* x  = (const float*)d_in[0];
    const float* Wq = (const float*)d_in[1];
    const float* bq = (const float*)d_in[2];
    const float* Wk = (const float*)d_in[3];
    const float* bk = (const float*)d_in[4];
    const float* Wv = (const float*)d_in[5];
    const float* bv = (const float*)d_in[6];
    const float* Wo = (const float*)d_in[7];
    const float* bo = (const float*)d_in[8];
    float* out = (float*)d_out;

    const size_t NX = 8192ull * 1024ull;
    const size_t NW = 1024ull * 1024ull;
    u16* p = (u16*)d_ws;
    u16* x16  = p; p += NX;
    u16* Wq16 = p; p += NW;
    u16* Wk16 = p; p += NW;
    u16* Wv16 = p; p += NW;
    u16* Wo16 = p; p += NW;
    u16* Qb   = p; p += NX;
    u16* Kb   = p; p += NX;
    u16* Vtb  = p; p += NX;
    u16* cx   = p; p += NX;
    if ((size_t)((char*)p - (char*)d_ws) > ws_size) return;

    dim3 blk(256);
    cast_all_f16<<<dim3(512, 5), blk, 0, stream>>>(
        x, Wq, Wk, Wv, Wo, x16, Wq16, Wk16, Wv16, Wo16,
        (int)(NX / 4), (int)(NW / 4));

    const float qscale = 0.125f * 1.44269504088896f;   // fold 1/sqrt(dk) * log2(e)
    gemm_qkv<<<dim3(64, 8, 3), blk, 0, stream>>>(
        x16, Wq16, Wk16, Wv16, bq, bk, bv, Qb, Kb, Vtb, qscale);

    attn_flash<<<dim3(16, 64), dim3(512), 0, stream>>>(Qb, Kb, Vtb, cx);

    gemm_o<<<dim3(64, 8), blk, 0, stream>>>(cx, Wo16, bo, out);
}